// Round 4
// baseline (243.409 us; speedup 1.0000x reference)
//
#include <hip/hip_runtime.h>

// Multi-head causal attention fwd, B=2 S=2048 D=1024 H=16 DK=DV=64.
// fp32 I/O; internal bf16 MFMA pipeline.
// Dispatches: convert, fused-QKV gemm, memset(partials), flash-attn,
//             combine(split-K qts), final gemm.
// v10: split-K attention. Fixed-shift softmax (no max) makes partials
// additive: qt>=16 k-loops split across 2 blocks (max serial chain 16->8),
// partial O^T/l atomicAdd'ed into f32 buffers, combined by a tiny kernel.
// qt<16 blocks write final output directly (v8 path). Padding mask baked
// out of the inner loop: V rows pre-zeroed at projection; l-MFMA uses a
// per-key valid fragment instead of ones. Conflict-free XOR-swizzled LDS.

typedef __bf16 bf16;
typedef __bf16 bf16x4 __attribute__((ext_vector_type(4)));
typedef __bf16 bf16x8 __attribute__((ext_vector_type(8)));
typedef float  f32x4  __attribute__((ext_vector_type(4)));

#define B_  2
#define S_  2048
#define D_  1024
#define H_  16
#define HD  64
#define NEG_BIG (-3.0e38f)
#define SCALE_LOG2E 0.1803368801111204f   // (1/8) * log2(e)

#define OPART_BYTES (32u * 16u * 64u * 64u * 4u)   // 8 MiB  [bh][qt-16][q][dv]
#define LPART_BYTES (32u * 16u * 64u * 4u)         // 128 KiB [bh][qt-16][q]

__device__ __forceinline__ void lds16(const void* g, void* l) {
    __builtin_amdgcn_global_load_lds((const __attribute__((address_space(1))) void*)g,
                                     (__attribute__((address_space(3))) void*)l, 16, 0, 0);
}

__device__ __forceinline__ f32x4 mfma16(bf16x8 a, bf16x8 b, f32x4 c) {
    return __builtin_amdgcn_mfma_f32_16x16x32_bf16(a, b, c, 0, 0, 0);
}

// ---------------- fp32 -> bf16 convert pre-pass (+ valid table) -------------
__global__ __launch_bounds__(256) void convert_k(const float* __restrict__ X,
                                                 const float* __restrict__ wq,
                                                 const float* __restrict__ wk,
                                                 const float* __restrict__ wv,
                                                 const float* __restrict__ wo,
                                                 const float* __restrict__ pm,
                                                 bf16* __restrict__ dst,
                                                 bf16* __restrict__ validB) {
    const int gid = blockIdx.x * 256 + threadIdx.x;
    const int i   = gid * 4;
    const float* src;
    int off;
    if      (i < (4 << 20)) { src = X;  off = 0; }
    else if (i < (5 << 20)) { src = wq; off = 4 << 20; }
    else if (i < (6 << 20)) { src = wk; off = 5 << 20; }
    else if (i < (7 << 20)) { src = wv; off = 6 << 20; }
    else                    { src = wo; off = 7 << 20; }
    const float4 v = *(const float4*)(src + (i - off));
    bf16x4 p;
    p[0] = (bf16)v.x; p[1] = (bf16)v.y; p[2] = (bf16)v.z; p[3] = (bf16)v.w;
    *(bf16x4*)(dst + i) = p;
    if (gid < (B_ * S_) / 4) {           // valid[key] = 1 - padded
        const float4 m = *(const float4*)(pm + gid * 4);
        bf16x4 q;
        q[0] = (bf16)((m.x > 0.f) ? 0.f : 1.f);
        q[1] = (bf16)((m.y > 0.f) ? 0.f : 1.f);
        q[2] = (bf16)((m.z > 0.f) ? 0.f : 1.f);
        q[3] = (bf16)((m.w > 0.f) ? 0.f : 1.f);
        *(bf16x4*)(validB + gid * 4) = q;
    }
}

// ---------------- fused QKV GEMM (768 blocks = 3/CU) ----------------
// seg 0: Q = X Wq^T (+bq)*SCALE_LOG2E -> [B,H,S,64]
// seg 1: K = X Wk^T (+bk)             -> [B,H,S,64]
// seg 2: V = (X Wv^T (+bv)) * valid   -> [B,H,64,S] (padded keys zeroed)
__global__ __launch_bounds__(256) void gemm_qkv(const bf16* __restrict__ A,
                                                const bf16* __restrict__ Wq,
                                                const bf16* __restrict__ Wk,
                                                const bf16* __restrict__ Wv,
                                                const float* __restrict__ bq,
                                                const float* __restrict__ bk,
                                                const float* __restrict__ bv,
                                                const float* __restrict__ pm,
                                                bf16* __restrict__ Qw,
                                                bf16* __restrict__ Kw,
                                                bf16* __restrict__ Vw) {
    constexpr int K = 1024;
    __shared__ bf16 sA[128 * 32];
    __shared__ bf16 sB[128 * 32];
    const int tid  = threadIdx.x;
    const int l15  = tid & 15;
    const int quad = (tid & 63) >> 4;
    const int wid  = tid >> 6;
    const int seg  = blockIdx.x >> 3;
    const int bn   = blockIdx.x & 7;
    const int bm   = blockIdx.y;
    const int wm   = (wid >> 1) * 64;
    const int wn   = (wid & 1) * 64;

    const bf16* W    = (seg == 0) ? Wq : (seg == 1) ? Wk : Wv;
    const float* bias = (seg == 0) ? bq : (seg == 1) ? bk : bv;

    const bf16* Ab = A + (size_t)bm * 128 * K;
    const bf16* Wb = W + (size_t)bn * 128 * K;

    f32x4 acc[4][4] = {};

    for (int k0 = 0; k0 < K; k0 += 32) {
        __syncthreads();
        #pragma unroll
        for (int it = 0; it < 2; ++it) {
            int c = it * 256 + tid;
            int row = c >> 2, c8 = c & 3;
            lds16(Ab + row * K + k0 + c8 * 8, (char*)sA + c * 16);
            lds16(Wb + row * K + k0 + c8 * 8, (char*)sB + c * 16);
        }
        __syncthreads();
        bf16x8 af[4], bfr[4];
        #pragma unroll
        for (int i = 0; i < 4; ++i)
            af[i] = *(const bf16x8*)&sA[(wm + i * 16 + l15) * 32 + quad * 8];
        #pragma unroll
        for (int i = 0; i < 4; ++i)
            bfr[i] = *(const bf16x8*)&sB[(wn + i * 16 + l15) * 32 + quad * 8];
        #pragma unroll
        for (int mi = 0; mi < 4; ++mi)
            #pragma unroll
            for (int ni = 0; ni < 4; ++ni)
                acc[mi][ni] = mfma16(af[mi], bfr[ni], acc[mi][ni]);
    }

    #pragma unroll
    for (int ni = 0; ni < 4; ++ni) {
        const int n  = bn * 128 + wn + ni * 16 + l15;
        const float bv_ = bias[n];
        const int h = n >> 6;
        #pragma unroll
        for (int mi = 0; mi < 4; ++mi) {
            const int m0 = bm * 128 + wm + mi * 16 + quad * 4;
            if (seg == 2) {   // V transposed: [B,H,64,S], padded keys zeroed
                const int dv = n & 63;
                const int b = m0 >> 11, s = m0 & 2047;
                const float4 pmv = *(const float4*)&pm[b * S_ + s];
                bf16x4 pack;
                #pragma unroll
                for (int r = 0; r < 4; ++r) {
                    const float vm = (((const float*)&pmv)[r] > 0.f) ? 0.f : 1.f;
                    pack[r] = (bf16)((acc[mi][ni][r] + bv_) * vm);
                }
                *(bf16x4*)&Vw[(((size_t)(b * H_ + h) * HD + dv) << 11) + s] = pack;
            } else {          // Q,K: [B,H,S,64]
                bf16* C = (seg == 0) ? Qw : Kw;
                const float qs = (seg == 0) ? SCALE_LOG2E : 1.0f;
                const int dk = n & 63;
                #pragma unroll
                for (int r = 0; r < 4; ++r) {
                    const int m = m0 + r, b = m >> 11, s = m & 2047;
                    C[(((size_t)(b * H_ + h) << 11) + s) * HD + dk] =
                        (bf16)((acc[mi][ni][r] + bv_) * qs);
                }
            }
        }
    }
}

// ---------------- final GEMM: out fp32 = A @ Wo^T + bias (512 blocks) -------
__global__ __launch_bounds__(256) void gemm_fin(const bf16* __restrict__ A,
                                                const bf16* __restrict__ W,
                                                const float* __restrict__ bias,
                                                float* __restrict__ C) {
    constexpr int N = 1024, K = 1024;
    __shared__ bf16 sA[64 * 32];
    __shared__ bf16 sB[128 * 32];
    const int tid  = threadIdx.x;
    const int l15  = tid & 15;
    const int quad = (tid & 63) >> 4;
    const int wid  = tid >> 6;
    const int bm   = blockIdx.x >> 3;
    const int bn   = blockIdx.x & 7;
    const int wm   = (wid & 1) * 32;
    const int wn   = (wid >> 1) * 64;

    const bf16* Ab = A + (size_t)bm * 64 * K;
    const bf16* Wb = W + (size_t)bn * 128 * K;

    f32x4 acc[2][4] = {};

    for (int k0 = 0; k0 < K; k0 += 32) {
        __syncthreads();
        {
            int c = tid, row = c >> 2, c8 = c & 3;
            lds16(Ab + row * K + k0 + c8 * 8, (char*)sA + c * 16);
        }
        #pragma unroll
        for (int it = 0; it < 2; ++it) {
            int c = it * 256 + tid;
            int row = c >> 2, c8 = c & 3;
            lds16(Wb + row * K + k0 + c8 * 8, (char*)sB + c * 16);
        }
        __syncthreads();
        bf16x8 af[2], bfr[4];
        #pragma unroll
        for (int i = 0; i < 2; ++i)
            af[i] = *(const bf16x8*)&sA[(wm + i * 16 + l15) * 32 + quad * 8];
        #pragma unroll
        for (int i = 0; i < 4; ++i)
            bfr[i] = *(const bf16x8*)&sB[(wn + i * 16 + l15) * 32 + quad * 8];
        #pragma unroll
        for (int mi = 0; mi < 2; ++mi)
            #pragma unroll
            for (int ni = 0; ni < 4; ++ni)
                acc[mi][ni] = mfma16(af[mi], bfr[ni], acc[mi][ni]);
    }

    #pragma unroll
    for (int ni = 0; ni < 4; ++ni) {
        const int n  = bn * 128 + wn + ni * 16 + l15;
        const float bv = bias[n];
        #pragma unroll
        for (int mi = 0; mi < 2; ++mi) {
            const int m0 = bm * 64 + wm + mi * 16 + quad * 4;
            #pragma unroll
            for (int r = 0; r < 4; ++r)
                C[(size_t)(m0 + r) * N + n] = acc[mi][ni][r] + bv;
        }
    }
}

// ---------------- Flash attention v10 (split-K) ----------------
// 1536 blocks = 32 bh x 48 work items, 256 threads (4 waves), 32 KiB LDS
// (5 blocks/CU resident). Items (dispatch order = largest first):
//   w in [0,32): qt = 16+(w>>1), half (w&1) of its k-range (4-8 tiles)
//                -> partial O^T/l atomicAdd'ed into Opart/Lpart.
//   w in [32,48): qt = 47-w (15..0), full k-range (8..1 tiles)
//                -> final normalized store to Aout.
// Per tile: S^T = K Q^T (permuted K rows -> P^T packs lane-locally),
// l = valid x P^T on the MFMA pipe (padding mask baked into valid + V).
__global__ __launch_bounds__(256, 4) void attn_k(const bf16* __restrict__ Q,
                                                 const bf16* __restrict__ K,
                                                 const bf16* __restrict__ Vt,
                                                 const bf16* __restrict__ validB,
                                                 float* __restrict__ Opart,
                                                 float* __restrict__ Lpart,
                                                 bf16* __restrict__ Aout) {
    __shared__ bf16 sK_[2 * 128 * 32];   // 16K [kk][krow][32]
    __shared__ bf16 sV[4 * 64 * 32];     // 16K [kc][dv][32]   (V^T)
    const int tid  = threadIdx.x;
    const int l15  = tid & 15;
    const int quad = (tid & 63) >> 4;
    const int wid  = tid >> 6;           // 0..3 -> q quarter
    const int bh   = blockIdx.x & 31;
    const int w    = blockIdx.x >> 5;    // 0..47
    const int b    = bh >> 4;
    const int h    = bh & 15;

    int qt, nkt, kt0, kte;
    bool split;
    if (w < 32) {                        // split halves of qt in [16,31]
        qt  = 16 + (w >> 1);
        nkt = (qt >> 1) + 1;             // 9..16
        const int kmid = nkt >> 1;
        split = true;
        kt0 = (w & 1) ? kmid : 0;
        kte = (w & 1) ? nkt  : kmid;
    } else {                             // whole qt in [0,15], largest first
        qt  = 47 - w;
        nkt = (qt >> 1) + 1;             // 8..1
        split = false;
        kt0 = 0; kte = nkt;
    }

    const bf16* Qg = Q  + (size_t)bh * S_ * HD;
    const bf16* Kg = K  + (size_t)bh * S_ * HD;
    const bf16* Vg = Vt + (size_t)bh * HD * S_;
    const bf16* vB = validB + b * S_;

    // Q B-frags: n=q=l15, k=kk*32+quad*8+jj
    bf16x8 qb[2];
    #pragma unroll
    for (int kk = 0; kk < 2; ++kk)
        qb[kk] = *(const bf16x8*)&Qg[(qt * 64 + wid * 16 + l15) * HD + kk * 32 + quad * 8];

    // permuted K row: lane l15 of frag f holds key (l15>>2)*8 + f*4 + (l15&3)
    const int krow0 = (l15 >> 2) * 8 + (l15 & 3);
    const int qg    = qt * 64 + wid * 16 + l15;   // this lane's global q (col)
    // conflict-free swizzled chunk offsets (elements)
    const int ckx = (quad ^ (((l15 >> 1) & 1) | (((l15 >> 2) & 1) << 1))) * 8;
    const int cvx = (quad ^ (((l15 >> 1) & 1) | (((l15 >> 3) & 1) << 1))) * 8;

    f32x4 o[4]  = {};                    // O^T: rows dv=dvf*16+quad*4+r, col q=l15
    f32x4 lacc  = {};                    // l[q], replicated

    for (int kt = kt0; kt < kte; ++kt) {
        __syncthreads();                 // prev compute done with sK_/sV
        #pragma unroll
        for (int it = 0; it < 4; ++it) {
            int c = it * 256 + tid;
            { int pl = c >> 9, row = (c >> 2) & 127, c8 = c & 3;
              int sw = c8 ^ (((row >> 1) & 1) | (((row >> 3) & 1) << 1));
              lds16(Kg + ((size_t)kt * 128 + row) * HD + pl * 32 + sw * 8,
                    (char*)sK_ + c * 16); }
            { int kc = c >> 8, dv = (c >> 2) & 63, c8 = c & 3;
              int sw = c8 ^ (((dv >> 1) & 1) | (((dv >> 3) & 1) << 1));
              lds16(Vg + (size_t)kt * 128 + (size_t)dv * S_ + kc * 32 + sw * 8,
                    (char*)sV + c * 16); }
        }
        // valid A-frags for the 4 key groups (tiny, L1-resident)
        bf16x8 vf[4];
        #pragma unroll
        for (int g = 0; g < 4; ++g)
            vf[g] = *(const bf16x8*)&vB[kt * 128 + g * 32 + quad * 8];
        __syncthreads();                 // staging drained & visible

        const bool lastt = (kt == nkt - 1);
        #pragma unroll
        for (int g = 0; g < 4; ++g) {
            // S^T for 32-key group g: C rows = keys (permuted back), cols = q
            f32x4 s[2] = {};
            #pragma unroll
            for (int f = 0; f < 2; ++f)
                #pragma unroll
                for (int kk = 0; kk < 2; ++kk) {
                    bf16x8 ka = *(const bf16x8*)
                        &sK_[(kk * 128 + g * 32 + krow0 + f * 4) * 32 + ckx];
                    s[f] = mfma16(ka, qb[kk], s[f]);
                }
            // exp2 -> P^T B-frag (lane-local pack); causal only on last tile
            bf16x8 pb;
            #pragma unroll
            for (int f = 0; f < 2; ++f)
                #pragma unroll
                for (int r = 0; r < 4; ++r) {
                    float v = s[f][r];
                    if (lastt && (kt * 128 + g * 32 + quad * 8 + f * 4 + r > qg))
                        v = NEG_BIG;
                    pb[f * 4 + r] = (bf16)exp2f(v);
                }
            lacc = mfma16(vf[g], pb, lacc);          // l += valid . P^T
            #pragma unroll
            for (int dvf = 0; dvf < 4; ++dvf) {
                bf16x8 va = *(const bf16x8*)
                    &sV[(g * 64 + dvf * 16 + l15) * 32 + cvx];
                o[dvf] = mfma16(va, pb, o[dvf]);     // O^T += V^T P^T
            }
        }
    }

    if (split) {
        // partial flush: atomicAdd O^T and l
        const int qth = qt - 16;
        const int q   = wid * 16 + l15;
        float* Ob = Opart + (((size_t)(bh * 16 + qth) * 64 + q) * 64);
        #pragma unroll
        for (int dvf = 0; dvf < 4; ++dvf)
            #pragma unroll
            for (int r = 0; r < 4; ++r)
                atomicAdd(Ob + dvf * 16 + quad * 4 + r, o[dvf][r]);
        if (quad == 0)
            atomicAdd(Lpart + (bh * 16 + qth) * 64 + q, lacc[0]);
    } else {
        // final: lane holds O[q][dv=dvf*16+quad*4+r], l[q]
        const float inv = 1.f / lacc[0];
        const size_t base = ((size_t)b * S_ + qg) * D_ + h * HD + quad * 4;
        #pragma unroll
        for (int dvf = 0; dvf < 4; ++dvf) {
            bf16x4 pk;
            #pragma unroll
            for (int r = 0; r < 4; ++r) pk[r] = (bf16)(o[dvf][r] * inv);
            *(bf16x4*)&Aout[base + dvf * 16] = pk;
        }
    }
}

// ---------------- combine split-K partials -> Aw (qt >= 16 only) ------------
__global__ __launch_bounds__(256) void combine_k(const float* __restrict__ Opart,
                                                 const float* __restrict__ Lpart,
                                                 bf16* __restrict__ Aw) {
    const int gid = blockIdx.x * 256 + threadIdx.x;  // 0..262143
    const int dvc = gid & 7;
    const int q   = (gid >> 3) & 63;
    const int qth = (gid >> 9) & 15;
    const int bh  = gid >> 13;                       // 0..31
    const float inv = 1.f / Lpart[(bh * 16 + qth) * 64 + q];
    const float* Ob = Opart + (((size_t)(bh * 16 + qth) * 64 + q) * 64) + dvc * 8;
    const float4 a0 = *(const float4*)(Ob);
    const float4 a1 = *(const float4*)(Ob + 4);
    bf16x8 p;
    p[0] = (bf16)(a0.x * inv); p[1] = (bf16)(a0.y * inv);
    p[2] = (bf16)(a0.z * inv); p[3] = (bf16)(a0.w * inv);
    p[4] = (bf16)(a1.x * inv); p[5] = (bf16)(a1.y * inv);
    p[6] = (bf16)(a1.z * inv); p[7] = (bf16)(a1.w * inv);
    const int b = bh >> 4, h = bh & 15;
    const int s = (16 + qth) * 64 + q;
    *(bf16x8*)&Aw[((size_t)(b * S_ + s)) * D_ + h * HD + dvc * 8] = p;
}

extern "C" void kernel_launch(void* const* d_in, const int* in_sizes, int n_in,
                              void* d_out, int out_size, void* d_ws, size_t ws_size,
                              hipStream_t stream) {
    const float* X   = (const float*)d_in[0];
    const float* pm  = (const float*)d_in[1];
    const float* wq  = (const float*)d_in[2];
    const float* bq  = (const float*)d_in[3];
    const float* wk  = (const float*)d_in[4];
    const float* bk  = (const float*)d_in[5];
    const float* wv  = (const float*)d_in[6];
    const float* bvb = (const float*)d_in[7];
    const float* wo  = (const float*)d_in[8];
    const float* bo  = (const float*)d_in[9];
    float* out = (float*)d_out;

    char* ws = (char*)d_ws;
    bf16* Xb  = (bf16*)(ws);                  // 4M elems  8 MiB (dead after qkv)
    bf16* Wqb = (bf16*)(ws + (8u  << 20));    // 2 MiB each (dead after qkv)
    bf16* Wkb = (bf16*)(ws + (10u << 20));
    bf16* Wvb = (bf16*)(ws + (12u << 20));
    bf16* Wob = (bf16*)(ws + (14u << 20));    // live until gemm_fin
    bf16* Qw  = (bf16*)(ws + (16u << 20));    // [B,H,S,64]  8 MiB
    bf16* Kw  = (bf16*)(ws + (24u << 20));    // [B,H,S,64]  8 MiB
    bf16* Vw  = (bf16*)(ws + (32u << 20));    // [B,H,64,S]  8 MiB
    bf16* Aw  = (bf16*)(ws + (40u << 20));    // [B*S, 1024] 8 MiB
    // split-K partials overlay the dead Xb/Wq region after gemm_qkv:
    float* Opart = (float*)(ws);              // 8 MiB
    float* Lpart = (float*)(ws + OPART_BYTES);// 128 KiB
    bf16* validB = (bf16*)(ws + (48u << 20)); // 8 KiB

    convert_k<<<dim3(8192), dim3(256), 0, stream>>>(X, wq, wk, wv, wo, pm,
                                                    Xb, validB);
    gemm_qkv<<<dim3(24, 32), dim3(256), 0, stream>>>(Xb, Wqb, Wkb, Wvb,
                                                     bq, bk, bvb, pm,
                                                     Qw, Kw, Vw);
    hipMemsetAsync(Opart, 0, OPART_BYTES + LPART_BYTES, stream);
    attn_k<<<dim3(1536), dim3(256), 0, stream>>>(Qw, Kw, Vw, validB,
                                                 Opart, Lpart, Aw);
    combine_k<<<dim3(1024), dim3(256), 0, stream>>>(Opart, Lpart, Aw);
    gemm_fin<<<dim3(512), dim3(256), 0, stream>>>(Aw, Wob, bo, out);
}

// Round 5
// 207.739 us; speedup vs baseline: 1.1717x; 1.1717x over previous
//
#include <hip/hip_runtime.h>

// Multi-head causal attention fwd, B=2 S=2048 D=1024 H=16 DK=DV=64.
// fp32 I/O; internal bf16 MFMA pipeline.
// Dispatches: convert, fused-QKV gemm, flash-attn(split-K), combine, final gemm.
// v11: v10's split-K decomposition with a contention-free flush:
//  - each split block (qt>=18, half k-range) writes a PRIVATE 16KB f32
//    partial slot with plain float4 stores (no atomics, no memset);
//  - combine kernel adds the two slots and normalizes into Aw;
//  - 46-entry descending-length item table -> longest chains dispatch first,
//    max serial chain 9 tile-units (was 16), grid 1472 (~5 resident/CU);
//  - inner loop identical to v10 (= v8 + XOR swizzle + valid-baked mask).

typedef __bf16 bf16;
typedef __bf16 bf16x4 __attribute__((ext_vector_type(4)));
typedef __bf16 bf16x8 __attribute__((ext_vector_type(8)));
typedef float  f32x4  __attribute__((ext_vector_type(4)));

#define B_  2
#define S_  2048
#define D_  1024
#define H_  16
#define HD  64
#define NEG_BIG (-3.0e38f)
#define SCALE_LOG2E 0.1803368801111204f   // (1/8) * log2(e)

// split-K partials: qt in [18,31], 2 slots each, per bh. 32*28 slots.
// Opart slot = 64q x 64dv f32 = 16 KB; total = 14 MiB (overlays dead Xb..Wvb).
#define NSPLIT_QT 14
#define SLOTS_PER_BH (2 * NSPLIT_QT)

__device__ __forceinline__ void lds16(const void* g, void* l) {
    __builtin_amdgcn_global_load_lds((const __attribute__((address_space(1))) void*)g,
                                     (__attribute__((address_space(3))) void*)l, 16, 0, 0);
}

__device__ __forceinline__ f32x4 mfma16(bf16x8 a, bf16x8 b, f32x4 c) {
    return __builtin_amdgcn_mfma_f32_16x16x32_bf16(a, b, c, 0, 0, 0);
}

// item table: qt | kt0<<8 | kte<<16, sorted by descending chain length.
#define IT(qt, k0, ke) ((uint32_t)(qt) | ((uint32_t)(k0) << 8) | ((uint32_t)(ke) << 16))
__device__ __constant__ uint32_t g_items[46] = {
    IT(16,0,9),  IT(17,0,9),                                            // len 9
    IT(30,0,8),  IT(30,8,16), IT(31,0,8),  IT(31,8,16),                 // len 8
    IT(28,0,8),  IT(29,0,8),  IT(14,0,8),  IT(15,0,8),                  // len 8
    IT(28,8,15), IT(29,8,15), IT(26,0,7),  IT(26,7,14),                 // len 7
    IT(27,0,7),  IT(27,7,14), IT(24,0,7),  IT(25,0,7),                  // len 7
    IT(12,0,7),  IT(13,0,7),                                            // len 7
    IT(24,7,13), IT(25,7,13), IT(22,0,6),  IT(22,6,12),                 // len 6
    IT(23,0,6),  IT(23,6,12), IT(20,0,6),  IT(21,0,6),                  // len 6
    IT(10,0,6),  IT(11,0,6),                                            // len 6
    IT(20,6,11), IT(21,6,11), IT(18,0,5),  IT(18,5,10),                 // len 5
    IT(19,0,5),  IT(19,5,10), IT(8,0,5),   IT(9,0,5),                   // len 5
    IT(6,0,4),   IT(7,0,4),                                             // len 4
    IT(4,0,3),   IT(5,0,3),                                             // len 3
    IT(2,0,2),   IT(3,0,2),                                             // len 2
    IT(0,0,1),   IT(1,0,1)                                              // len 1
};

// ---------------- fp32 -> bf16 convert pre-pass (+ valid table) -------------
__global__ __launch_bounds__(256) void convert_k(const float* __restrict__ X,
                                                 const float* __restrict__ wq,
                                                 const float* __restrict__ wk,
                                                 const float* __restrict__ wv,
                                                 const float* __restrict__ wo,
                                                 const float* __restrict__ pm,
                                                 bf16* __restrict__ dst,
                                                 bf16* __restrict__ validB) {
    const int gid = blockIdx.x * 256 + threadIdx.x;
    const int i   = gid * 4;
    const float* src;
    int off;
    if      (i < (4 << 20)) { src = X;  off = 0; }
    else if (i < (5 << 20)) { src = wq; off = 4 << 20; }
    else if (i < (6 << 20)) { src = wk; off = 5 << 20; }
    else if (i < (7 << 20)) { src = wv; off = 6 << 20; }
    else                    { src = wo; off = 7 << 20; }
    const float4 v = *(const float4*)(src + (i - off));
    bf16x4 p;
    p[0] = (bf16)v.x; p[1] = (bf16)v.y; p[2] = (bf16)v.z; p[3] = (bf16)v.w;
    *(bf16x4*)(dst + i) = p;
    if (gid < (B_ * S_) / 4) {           // valid[key] = 1 - padded
        const float4 m = *(const float4*)(pm + gid * 4);
        bf16x4 q;
        q[0] = (bf16)((m.x > 0.f) ? 0.f : 1.f);
        q[1] = (bf16)((m.y > 0.f) ? 0.f : 1.f);
        q[2] = (bf16)((m.z > 0.f) ? 0.f : 1.f);
        q[3] = (bf16)((m.w > 0.f) ? 0.f : 1.f);
        *(bf16x4*)(validB + gid * 4) = q;
    }
}

// ---------------- fused QKV GEMM (768 blocks = 3/CU) ----------------
// seg 0: Q = X Wq^T (+bq)*SCALE_LOG2E -> [B,H,S,64]
// seg 1: K = X Wk^T (+bk)             -> [B,H,S,64]
// seg 2: V = (X Wv^T (+bv)) * valid   -> [B,H,64,S] (padded keys zeroed)
__global__ __launch_bounds__(256) void gemm_qkv(const bf16* __restrict__ A,
                                                const bf16* __restrict__ Wq,
                                                const bf16* __restrict__ Wk,
                                                const bf16* __restrict__ Wv,
                                                const float* __restrict__ bq,
                                                const float* __restrict__ bk,
                                                const float* __restrict__ bv,
                                                const float* __restrict__ pm,
                                                bf16* __restrict__ Qw,
                                                bf16* __restrict__ Kw,
                                                bf16* __restrict__ Vw) {
    constexpr int K = 1024;
    __shared__ bf16 sA[128 * 32];
    __shared__ bf16 sB[128 * 32];
    const int tid  = threadIdx.x;
    const int l15  = tid & 15;
    const int quad = (tid & 63) >> 4;
    const int wid  = tid >> 6;
    const int seg  = blockIdx.x >> 3;
    const int bn   = blockIdx.x & 7;
    const int bm   = blockIdx.y;
    const int wm   = (wid >> 1) * 64;
    const int wn   = (wid & 1) * 64;

    const bf16* W    = (seg == 0) ? Wq : (seg == 1) ? Wk : Wv;
    const float* bias = (seg == 0) ? bq : (seg == 1) ? bk : bv;

    const bf16* Ab = A + (size_t)bm * 128 * K;
    const bf16* Wb = W + (size_t)bn * 128 * K;

    f32x4 acc[4][4] = {};

    for (int k0 = 0; k0 < K; k0 += 32) {
        __syncthreads();
        #pragma unroll
        for (int it = 0; it < 2; ++it) {
            int c = it * 256 + tid;
            int row = c >> 2, c8 = c & 3;
            lds16(Ab + row * K + k0 + c8 * 8, (char*)sA + c * 16);
            lds16(Wb + row * K + k0 + c8 * 8, (char*)sB + c * 16);
        }
        __syncthreads();
        bf16x8 af[4], bfr[4];
        #pragma unroll
        for (int i = 0; i < 4; ++i)
            af[i] = *(const bf16x8*)&sA[(wm + i * 16 + l15) * 32 + quad * 8];
        #pragma unroll
        for (int i = 0; i < 4; ++i)
            bfr[i] = *(const bf16x8*)&sB[(wn + i * 16 + l15) * 32 + quad * 8];
        #pragma unroll
        for (int mi = 0; mi < 4; ++mi)
            #pragma unroll
            for (int ni = 0; ni < 4; ++ni)
                acc[mi][ni] = mfma16(af[mi], bfr[ni], acc[mi][ni]);
    }

    #pragma unroll
    for (int ni = 0; ni < 4; ++ni) {
        const int n  = bn * 128 + wn + ni * 16 + l15;
        const float bv_ = bias[n];
        const int h = n >> 6;
        #pragma unroll
        for (int mi = 0; mi < 4; ++mi) {
            const int m0 = bm * 128 + wm + mi * 16 + quad * 4;
            if (seg == 2) {   // V transposed: [B,H,64,S], padded keys zeroed
                const int dv = n & 63;
                const int b = m0 >> 11, s = m0 & 2047;
                const float4 pmv = *(const float4*)&pm[b * S_ + s];
                bf16x4 pack;
                #pragma unroll
                for (int r = 0; r < 4; ++r) {
                    const float vm = (((const float*)&pmv)[r] > 0.f) ? 0.f : 1.f;
                    pack[r] = (bf16)((acc[mi][ni][r] + bv_) * vm);
                }
                *(bf16x4*)&Vw[(((size_t)(b * H_ + h) * HD + dv) << 11) + s] = pack;
            } else {          // Q,K: [B,H,S,64]
                bf16* C = (seg == 0) ? Qw : Kw;
                const float qs = (seg == 0) ? SCALE_LOG2E : 1.0f;
                const int dk = n & 63;
                #pragma unroll
                for (int r = 0; r < 4; ++r) {
                    const int m = m0 + r, b = m >> 11, s = m & 2047;
                    C[(((size_t)(b * H_ + h) << 11) + s) * HD + dk] =
                        (bf16)((acc[mi][ni][r] + bv_) * qs);
                }
            }
        }
    }
}

// ---------------- final GEMM: out fp32 = A @ Wo^T + bias (512 blocks) -------
__global__ __launch_bounds__(256) void gemm_fin(const bf16* __restrict__ A,
                                                const bf16* __restrict__ W,
                                                const float* __restrict__ bias,
                                                float* __restrict__ C) {
    constexpr int N = 1024, K = 1024;
    __shared__ bf16 sA[64 * 32];
    __shared__ bf16 sB[128 * 32];
    const int tid  = threadIdx.x;
    const int l15  = tid & 15;
    const int quad = (tid & 63) >> 4;
    const int wid  = tid >> 6;
    const int bm   = blockIdx.x >> 3;
    const int bn   = blockIdx.x & 7;
    const int wm   = (wid & 1) * 32;
    const int wn   = (wid >> 1) * 64;

    const bf16* Ab = A + (size_t)bm * 64 * K;
    const bf16* Wb = W + (size_t)bn * 128 * K;

    f32x4 acc[2][4] = {};

    for (int k0 = 0; k0 < K; k0 += 32) {
        __syncthreads();
        {
            int c = tid, row = c >> 2, c8 = c & 3;
            lds16(Ab + row * K + k0 + c8 * 8, (char*)sA + c * 16);
        }
        #pragma unroll
        for (int it = 0; it < 2; ++it) {
            int c = it * 256 + tid;
            int row = c >> 2, c8 = c & 3;
            lds16(Wb + row * K + k0 + c8 * 8, (char*)sB + c * 16);
        }
        __syncthreads();
        bf16x8 af[2], bfr[4];
        #pragma unroll
        for (int i = 0; i < 2; ++i)
            af[i] = *(const bf16x8*)&sA[(wm + i * 16 + l15) * 32 + quad * 8];
        #pragma unroll
        for (int i = 0; i < 4; ++i)
            bfr[i] = *(const bf16x8*)&sB[(wn + i * 16 + l15) * 32 + quad * 8];
        #pragma unroll
        for (int mi = 0; mi < 2; ++mi)
            #pragma unroll
            for (int ni = 0; ni < 4; ++ni)
                acc[mi][ni] = mfma16(af[mi], bfr[ni], acc[mi][ni]);
    }

    #pragma unroll
    for (int ni = 0; ni < 4; ++ni) {
        const int n  = bn * 128 + wn + ni * 16 + l15;
        const float bv = bias[n];
        #pragma unroll
        for (int mi = 0; mi < 2; ++mi) {
            const int m0 = bm * 64 + wm + mi * 16 + quad * 4;
            #pragma unroll
            for (int r = 0; r < 4; ++r)
                C[(size_t)(m0 + r) * N + n] = acc[mi][ni][r] + bv;
        }
    }
}

// ---------------- Flash attention v11 (split-K, private partials) -----------
// 1472 blocks = 46 items x 32 bh, 256 threads (4 waves), 32 KiB LDS
// (5 blocks/CU resident). Items sorted descending by chain length (<=9).
// qt<18: full k-range, final normalized store. qt>=18: half k-range,
// private f32 partial slot (plain stores). Inner loop: S^T = K Q^T with
// permuted K rows (P^T packs lane-locally); l = valid x P^T on MFMA pipe.
__global__ __launch_bounds__(256, 4) void attn_k(const bf16* __restrict__ Q,
                                                 const bf16* __restrict__ K,
                                                 const bf16* __restrict__ Vt,
                                                 const bf16* __restrict__ validB,
                                                 float* __restrict__ Opart,
                                                 float* __restrict__ Lpart,
                                                 bf16* __restrict__ Aout) {
    __shared__ bf16 sK_[2 * 128 * 32];   // 16K [kk][krow][32]
    __shared__ bf16 sV[4 * 64 * 32];     // 16K [kc][dv][32]   (V^T)
    const int tid  = threadIdx.x;
    const int l15  = tid & 15;
    const int quad = (tid & 63) >> 4;
    const int wid  = tid >> 6;           // 0..3 -> q quarter
    const int bh   = blockIdx.x & 31;
    const int b    = bh >> 4;
    const int h    = bh & 15;

    const uint32_t itm = g_items[blockIdx.x >> 5];
    const int qt  = itm & 255;
    const int kt0 = (itm >> 8) & 255;
    const int kte = (itm >> 16) & 255;
    const int nkt = (qt >> 1) + 1;       // full causal range (for diag test)
    const bool split = (qt >= 18);

    const bf16* Qg = Q  + (size_t)bh * S_ * HD;
    const bf16* Kg = K  + (size_t)bh * S_ * HD;
    const bf16* Vg = Vt + (size_t)bh * HD * S_;
    const bf16* vB = validB + b * S_;

    // Q B-frags: n=q=l15, k=kk*32+quad*8+jj
    bf16x8 qb[2];
    #pragma unroll
    for (int kk = 0; kk < 2; ++kk)
        qb[kk] = *(const bf16x8*)&Qg[(qt * 64 + wid * 16 + l15) * HD + kk * 32 + quad * 8];

    // permuted K row: lane l15 of frag f holds key (l15>>2)*8 + f*4 + (l15&3)
    const int krow0 = (l15 >> 2) * 8 + (l15 & 3);
    const int qg    = qt * 64 + wid * 16 + l15;   // this lane's global q (col)
    // conflict-free swizzled chunk offsets (elements)
    const int ckx = (quad ^ (((l15 >> 1) & 1) | (((l15 >> 2) & 1) << 1))) * 8;
    const int cvx = (quad ^ (((l15 >> 1) & 1) | (((l15 >> 3) & 1) << 1))) * 8;

    f32x4 o[4]  = {};                    // O^T: rows dv=dvf*16+quad*4+r, col q=l15
    f32x4 lacc  = {};                    // l[q], replicated

    for (int kt = kt0; kt < kte; ++kt) {
        __syncthreads();                 // prev compute done with sK_/sV
        #pragma unroll
        for (int it = 0; it < 4; ++it) {
            int c = it * 256 + tid;
            { int pl = c >> 9, row = (c >> 2) & 127, c8 = c & 3;
              int sw = c8 ^ (((row >> 1) & 1) | (((row >> 3) & 1) << 1));
              lds16(Kg + ((size_t)kt * 128 + row) * HD + pl * 32 + sw * 8,
                    (char*)sK_ + c * 16); }
            { int kc = c >> 8, dv = (c >> 2) & 63, c8 = c & 3;
              int sw = c8 ^ (((dv >> 1) & 1) | (((dv >> 3) & 1) << 1));
              lds16(Vg + (size_t)kt * 128 + (size_t)dv * S_ + kc * 32 + sw * 8,
                    (char*)sV + c * 16); }
        }
        // valid A-frags for the 4 key groups (tiny, L1-resident)
        bf16x8 vf[4];
        #pragma unroll
        for (int g = 0; g < 4; ++g)
            vf[g] = *(const bf16x8*)&vB[kt * 128 + g * 32 + quad * 8];
        __syncthreads();                 // staging drained & visible

        const bool lastt = (kt == nkt - 1);
        #pragma unroll
        for (int g = 0; g < 4; ++g) {
            // S^T for 32-key group g: C rows = keys (permuted back), cols = q
            f32x4 s[2] = {};
            #pragma unroll
            for (int f = 0; f < 2; ++f)
                #pragma unroll
                for (int kk = 0; kk < 2; ++kk) {
                    bf16x8 ka = *(const bf16x8*)
                        &sK_[(kk * 128 + g * 32 + krow0 + f * 4) * 32 + ckx];
                    s[f] = mfma16(ka, qb[kk], s[f]);
                }
            // exp2 -> P^T B-frag (lane-local pack); causal only on last tile
            bf16x8 pb;
            #pragma unroll
            for (int f = 0; f < 2; ++f)
                #pragma unroll
                for (int r = 0; r < 4; ++r) {
                    float v = s[f][r];
                    if (lastt && (kt * 128 + g * 32 + quad * 8 + f * 4 + r > qg))
                        v = NEG_BIG;
                    pb[f * 4 + r] = (bf16)exp2f(v);
                }
            lacc = mfma16(vf[g], pb, lacc);          // l += valid . P^T
            #pragma unroll
            for (int dvf = 0; dvf < 4; ++dvf) {
                bf16x8 va = *(const bf16x8*)
                    &sV[(g * 64 + dvf * 16 + l15) * 32 + cvx];
                o[dvf] = mfma16(va, pb, o[dvf]);     // O^T += V^T P^T
            }
        }
    }

    if (split) {
        // private partial slot: plain stores, no contention
        const int sidx = (qt - 18) * 2 + (kt0 ? 1 : 0);
        const int slot = bh * SLOTS_PER_BH + sidx;
        const int q    = wid * 16 + l15;
        float* Ob = Opart + ((size_t)slot << 12) + q * 64 + quad * 4;
        #pragma unroll
        for (int dvf = 0; dvf < 4; ++dvf)
            *(f32x4*)(Ob + dvf * 16) = o[dvf];
        if (quad == 0) Lpart[slot * 64 + q] = lacc[0];
    } else {
        // final: lane holds O[q][dv=dvf*16+quad*4+r], l[q]
        const float inv = 1.f / lacc[0];
        const size_t base = ((size_t)b * S_ + qg) * D_ + h * HD + quad * 4;
        #pragma unroll
        for (int dvf = 0; dvf < 4; ++dvf) {
            bf16x4 pk;
            #pragma unroll
            for (int r = 0; r < 4; ++r) pk[r] = (bf16)(o[dvf][r] * inv);
            *(bf16x4*)&Aout[base + dvf * 16] = pk;
        }
    }
}

// ---------------- combine split-K partials -> Aw (qt >= 18 only) ------------
// 229376 threads: (bh 32) x (qth 14) x (q 64) x (dv-chunk 8), 896 blocks.
__global__ __launch_bounds__(256) void combine_k(const float* __restrict__ Opart,
                                                 const float* __restrict__ Lpart,
                                                 bf16* __restrict__ Aw) {
    const int gid  = blockIdx.x * 256 + threadIdx.x;
    const int dc   = gid & 7;
    const int q    = (gid >> 3) & 63;
    const int rest = gid >> 9;           // 0..447
    const int qth  = rest % NSPLIT_QT;
    const int bh   = rest / NSPLIT_QT;
    const int slot0 = bh * SLOTS_PER_BH + qth * 2;
    const float l = Lpart[slot0 * 64 + q] + Lpart[(slot0 + 1) * 64 + q];
    const float inv = 1.f / l;
    const float* O0 = Opart + ((size_t)slot0 << 12) + q * 64 + dc * 8;
    const float* O1 = O0 + 4096;
    const float4 a0 = *(const float4*)O0;
    const float4 a1 = *(const float4*)(O0 + 4);
    const float4 b0 = *(const float4*)O1;
    const float4 b1 = *(const float4*)(O1 + 4);
    bf16x8 p;
    p[0] = (bf16)((a0.x + b0.x) * inv); p[1] = (bf16)((a0.y + b0.y) * inv);
    p[2] = (bf16)((a0.z + b0.z) * inv); p[3] = (bf16)((a0.w + b0.w) * inv);
    p[4] = (bf16)((a1.x + b1.x) * inv); p[5] = (bf16)((a1.y + b1.y) * inv);
    p[6] = (bf16)((a1.z + b1.z) * inv); p[7] = (bf16)((a1.w + b1.w) * inv);
    const int b = bh >> 4, h = bh & 15;
    const int s = (18 + qth) * 64 + q;
    *(bf16x8*)&Aw[((size_t)(b * S_ + s)) * D_ + h * HD + dc * 8] = p;
}

extern "C" void kernel_launch(void* const* d_in, const int* in_sizes, int n_in,
                              void* d_out, int out_size, void* d_ws, size_t ws_size,
                              hipStream_t stream) {
    const float* X   = (const float*)d_in[0];
    const float* pm  = (const float*)d_in[1];
    const float* wq  = (const float*)d_in[2];
    const float* bq  = (const float*)d_in[3];
    const float* wk  = (const float*)d_in[4];
    const float* bk  = (const float*)d_in[5];
    const float* wv  = (const float*)d_in[6];
    const float* bvb = (const float*)d_in[7];
    const float* wo  = (const float*)d_in[8];
    const float* bo  = (const float*)d_in[9];
    float* out = (float*)d_out;

    char* ws = (char*)d_ws;
    bf16* Xb  = (bf16*)(ws);                  // 4M elems  8 MiB (dead after qkv)
    bf16* Wqb = (bf16*)(ws + (8u  << 20));    // 2 MiB each (dead after qkv)
    bf16* Wkb = (bf16*)(ws + (10u << 20));
    bf16* Wvb = (bf16*)(ws + (12u << 20));
    bf16* Wob = (bf16*)(ws + (14u << 20));    // live until gemm_fin
    bf16* Qw  = (bf16*)(ws + (16u << 20));    // [B,H,S,64]  8 MiB
    bf16* Kw  = (bf16*)(ws + (24u << 20));    // [B,H,S,64]  8 MiB
    bf16* Vw  = (bf16*)(ws + (32u << 20));    // [B,H,64,S]  8 MiB
    bf16* Aw  = (bf16*)(ws + (40u << 20));    // [B*S, 1024] 8 MiB
    // split-K partials overlay the dead Xb..Wvb region (14 MiB exactly):
    float* Opart = (float*)(ws);
    bf16*  validB = (bf16*)(ws + (48u << 20));          // 8 KiB
    float* Lpart  = (float*)(ws + (48u << 20) + 65536); // 224 KiB

    convert_k<<<dim3(8192), dim3(256), 0, stream>>>(X, wq, wk, wv, wo, pm,
                                                    Xb, validB);
    gemm_qkv<<<dim3(24, 32), dim3(256), 0, stream>>>(Xb, Wqb, Wkb, Wvb,
                                                     bq, bk, bvb, pm,
                                                     Qw, Kw, Vw);
    attn_k<<<dim3(1472), dim3(256), 0, stream>>>(Qw, Kw, Vw, validB,
                                                 Opart, Lpart, Aw);
    combine_k<<<dim3(896), dim3(256), 0, stream>>>(Opart, Lpart, Aw);
    gemm_fin<<<dim3(512), dim3(256), 0, stream>>>(Aw, Wob, bo, out);
}

// Round 6
// 197.857 us; speedup vs baseline: 1.2302x; 1.0499x over previous
//
#include <hip/hip_runtime.h>

// Multi-head causal attention fwd, B=2 S=2048 D=1024 H=16 DK=DV=64.
// fp32 I/O; internal bf16 MFMA pipeline.
// Dispatches: convert, fused-QKV gemm, flash-attn(split-K), combine, final gemm.
// v12: GEMMs fixed (attn identical to v11):
//  - XOR bank swizzle on LDS staging source + fragment reads (8-way -> free);
//  - 2-phase double-buffered K-loop: STAGE(next) issued BEFORE compute,
//    ONE barrier per K-step (was stage->barrier->compute->barrier with the
//    full staging latency exposed every iteration).

typedef __bf16 bf16;
typedef __bf16 bf16x4 __attribute__((ext_vector_type(4)));
typedef __bf16 bf16x8 __attribute__((ext_vector_type(8)));
typedef float  f32x4  __attribute__((ext_vector_type(4)));

#define B_  2
#define S_  2048
#define D_  1024
#define H_  16
#define HD  64
#define NEG_BIG (-3.0e38f)
#define SCALE_LOG2E 0.1803368801111204f   // (1/8) * log2(e)

// split-K partials: qt in [18,31], 2 slots each, per bh. 32*28 slots.
#define NSPLIT_QT 14
#define SLOTS_PER_BH (2 * NSPLIT_QT)

__device__ __forceinline__ void lds16(const void* g, void* l) {
    __builtin_amdgcn_global_load_lds((const __attribute__((address_space(1))) void*)g,
                                     (__attribute__((address_space(3))) void*)l, 16, 0, 0);
}

__device__ __forceinline__ f32x4 mfma16(bf16x8 a, bf16x8 b, f32x4 c) {
    return __builtin_amdgcn_mfma_f32_16x16x32_bf16(a, b, c, 0, 0, 0);
}

// item table: qt | kt0<<8 | kte<<16, sorted by descending chain length.
#define IT(qt, k0, ke) ((uint32_t)(qt) | ((uint32_t)(k0) << 8) | ((uint32_t)(ke) << 16))
__device__ __constant__ uint32_t g_items[46] = {
    IT(16,0,9),  IT(17,0,9),                                            // len 9
    IT(30,0,8),  IT(30,8,16), IT(31,0,8),  IT(31,8,16),                 // len 8
    IT(28,0,8),  IT(29,0,8),  IT(14,0,8),  IT(15,0,8),                  // len 8
    IT(28,8,15), IT(29,8,15), IT(26,0,7),  IT(26,7,14),                 // len 7
    IT(27,0,7),  IT(27,7,14), IT(24,0,7),  IT(25,0,7),                  // len 7
    IT(12,0,7),  IT(13,0,7),                                            // len 7
    IT(24,7,13), IT(25,7,13), IT(22,0,6),  IT(22,6,12),                 // len 6
    IT(23,0,6),  IT(23,6,12), IT(20,0,6),  IT(21,0,6),                  // len 6
    IT(10,0,6),  IT(11,0,6),                                            // len 6
    IT(20,6,11), IT(21,6,11), IT(18,0,5),  IT(18,5,10),                 // len 5
    IT(19,0,5),  IT(19,5,10), IT(8,0,5),   IT(9,0,5),                   // len 5
    IT(6,0,4),   IT(7,0,4),                                             // len 4
    IT(4,0,3),   IT(5,0,3),                                             // len 3
    IT(2,0,2),   IT(3,0,2),                                             // len 2
    IT(0,0,1),   IT(1,0,1)                                              // len 1
};

// ---------------- fp32 -> bf16 convert pre-pass (+ valid table) -------------
__global__ __launch_bounds__(256) void convert_k(const float* __restrict__ X,
                                                 const float* __restrict__ wq,
                                                 const float* __restrict__ wk,
                                                 const float* __restrict__ wv,
                                                 const float* __restrict__ wo,
                                                 const float* __restrict__ pm,
                                                 bf16* __restrict__ dst,
                                                 bf16* __restrict__ validB) {
    const int gid = blockIdx.x * 256 + threadIdx.x;
    const int i   = gid * 4;
    const float* src;
    int off;
    if      (i < (4 << 20)) { src = X;  off = 0; }
    else if (i < (5 << 20)) { src = wq; off = 4 << 20; }
    else if (i < (6 << 20)) { src = wk; off = 5 << 20; }
    else if (i < (7 << 20)) { src = wv; off = 6 << 20; }
    else                    { src = wo; off = 7 << 20; }
    const float4 v = *(const float4*)(src + (i - off));
    bf16x4 p;
    p[0] = (bf16)v.x; p[1] = (bf16)v.y; p[2] = (bf16)v.z; p[3] = (bf16)v.w;
    *(bf16x4*)(dst + i) = p;
    if (gid < (B_ * S_) / 4) {           // valid[key] = 1 - padded
        const float4 m = *(const float4*)(pm + gid * 4);
        bf16x4 q;
        q[0] = (bf16)((m.x > 0.f) ? 0.f : 1.f);
        q[1] = (bf16)((m.y > 0.f) ? 0.f : 1.f);
        q[2] = (bf16)((m.z > 0.f) ? 0.f : 1.f);
        q[3] = (bf16)((m.w > 0.f) ? 0.f : 1.f);
        *(bf16x4*)(validB + gid * 4) = q;
    }
}

// ---------------- fused QKV GEMM (768 blocks = 3/CU) ----------------
// seg 0: Q = X Wq^T (+bq)*SCALE_LOG2E -> [B,H,S,64]
// seg 1: K = X Wk^T (+bk)             -> [B,H,S,64]
// seg 2: V = (X Wv^T (+bv)) * valid   -> [B,H,64,S] (padded keys zeroed)
// v12: swizzled LDS + 2-phase double buffer, 1 barrier per K-step.
__global__ __launch_bounds__(256) void gemm_qkv(const bf16* __restrict__ A,
                                                const bf16* __restrict__ Wq,
                                                const bf16* __restrict__ Wk,
                                                const bf16* __restrict__ Wv,
                                                const float* __restrict__ bq,
                                                const float* __restrict__ bk,
                                                const float* __restrict__ bv,
                                                const float* __restrict__ pm,
                                                bf16* __restrict__ Qw,
                                                bf16* __restrict__ Kw,
                                                bf16* __restrict__ Vw) {
    constexpr int K = 1024;
    __shared__ bf16 sA[2][128 * 32];
    __shared__ bf16 sB[2][128 * 32];
    const int tid  = threadIdx.x;
    const int l15  = tid & 15;
    const int quad = (tid & 63) >> 4;
    const int wid  = tid >> 6;
    const int seg  = blockIdx.x >> 3;
    const int bn   = blockIdx.x & 7;
    const int bm   = blockIdx.y;
    const int wm   = (wid >> 1) * 64;
    const int wn   = (wid & 1) * 64;

    const bf16* W    = (seg == 0) ? Wq : (seg == 1) ? Wk : Wv;
    const float* bias = (seg == 0) ? bq : (seg == 1) ? bk : bv;

    const bf16* Ab = A + (size_t)bm * 128 * K;
    const bf16* Wb = W + (size_t)bn * 128 * K;

    f32x4 acc[4][4] = {};
    // swizzled read chunk: row = (mult of 32) + i*16 + l15 -> (row>>1)&3 = (l15>>1)&3
    const int rq = (quad ^ ((l15 >> 1) & 3)) * 8;

#define QSTAGE(BUF, K0) do {                                                    \
    _Pragma("unroll")                                                           \
    for (int it_ = 0; it_ < 2; ++it_) {                                         \
        int c_ = it_ * 256 + tid;                                               \
        int row_ = c_ >> 2, c8_ = c_ & 3;                                       \
        int sw_ = c8_ ^ ((row_ >> 1) & 3);                                      \
        lds16(Ab + row_ * K + (K0) + sw_ * 8, (char*)sA[BUF] + c_ * 16);        \
        lds16(Wb + row_ * K + (K0) + sw_ * 8, (char*)sB[BUF] + c_ * 16);        \
    } } while (0)

    QSTAGE(0, 0);
    __syncthreads();
    int cur = 0;
    for (int k0 = 0; k0 < K; k0 += 32) {
        if (k0 + 32 < K) QSTAGE(cur ^ 1, k0 + 32);    // overlaps compute below
        bf16x8 af[4], bfr[4];
        #pragma unroll
        for (int i = 0; i < 4; ++i)
            af[i] = *(const bf16x8*)&sA[cur][(wm + i * 16 + l15) * 32 + rq];
        #pragma unroll
        for (int i = 0; i < 4; ++i)
            bfr[i] = *(const bf16x8*)&sB[cur][(wn + i * 16 + l15) * 32 + rq];
        #pragma unroll
        for (int mi = 0; mi < 4; ++mi)
            #pragma unroll
            for (int ni = 0; ni < 4; ++ni)
                acc[mi][ni] = mfma16(af[mi], bfr[ni], acc[mi][ni]);
        __syncthreads();                              // next buf staged+visible
        cur ^= 1;
    }
#undef QSTAGE

    #pragma unroll
    for (int ni = 0; ni < 4; ++ni) {
        const int n  = bn * 128 + wn + ni * 16 + l15;
        const float bv_ = bias[n];
        const int h = n >> 6;
        #pragma unroll
        for (int mi = 0; mi < 4; ++mi) {
            const int m0 = bm * 128 + wm + mi * 16 + quad * 4;
            if (seg == 2) {   // V transposed: [B,H,64,S], padded keys zeroed
                const int dv = n & 63;
                const int b = m0 >> 11, s = m0 & 2047;
                const float4 pmv = *(const float4*)&pm[b * S_ + s];
                bf16x4 pack;
                #pragma unroll
                for (int r = 0; r < 4; ++r) {
                    const float vm = (((const float*)&pmv)[r] > 0.f) ? 0.f : 1.f;
                    pack[r] = (bf16)((acc[mi][ni][r] + bv_) * vm);
                }
                *(bf16x4*)&Vw[(((size_t)(b * H_ + h) * HD + dv) << 11) + s] = pack;
            } else {          // Q,K: [B,H,S,64]
                bf16* C = (seg == 0) ? Qw : Kw;
                const float qs = (seg == 0) ? SCALE_LOG2E : 1.0f;
                const int dk = n & 63;
                #pragma unroll
                for (int r = 0; r < 4; ++r) {
                    const int m = m0 + r, b = m >> 11, s = m & 2047;
                    C[(((size_t)(b * H_ + h) << 11) + s) * HD + dk] =
                        (bf16)((acc[mi][ni][r] + bv_) * qs);
                }
            }
        }
    }
}

// ---------------- final GEMM: out fp32 = A @ Wo^T + bias (512 blocks) -------
// v12: swizzled LDS + 2-phase double buffer, 1 barrier per K-step.
__global__ __launch_bounds__(256) void gemm_fin(const bf16* __restrict__ A,
                                                const bf16* __restrict__ W,
                                                const float* __restrict__ bias,
                                                float* __restrict__ C) {
    constexpr int N = 1024, K = 1024;
    __shared__ bf16 sA[2][64 * 32];
    __shared__ bf16 sB[2][128 * 32];
    const int tid  = threadIdx.x;
    const int l15  = tid & 15;
    const int quad = (tid & 63) >> 4;
    const int wid  = tid >> 6;
    const int bm   = blockIdx.x >> 3;
    const int bn   = blockIdx.x & 7;
    const int wm   = (wid & 1) * 32;
    const int wn   = (wid >> 1) * 64;

    const bf16* Ab = A + (size_t)bm * 64 * K;
    const bf16* Wb = W + (size_t)bn * 128 * K;

    f32x4 acc[2][4] = {};
    const int rq = (quad ^ ((l15 >> 1) & 3)) * 8;

#define FSTAGE(BUF, K0) do {                                                    \
    {   int c_ = tid;                                                           \
        int row_ = c_ >> 2, c8_ = c_ & 3;                                       \
        int sw_ = c8_ ^ ((row_ >> 1) & 3);                                      \
        lds16(Ab + row_ * K + (K0) + sw_ * 8, (char*)sA[BUF] + c_ * 16); }      \
    _Pragma("unroll")                                                           \
    for (int it_ = 0; it_ < 2; ++it_) {                                         \
        int c_ = it_ * 256 + tid;                                               \
        int row_ = c_ >> 2, c8_ = c_ & 3;                                       \
        int sw_ = c8_ ^ ((row_ >> 1) & 3);                                      \
        lds16(Wb + row_ * K + (K0) + sw_ * 8, (char*)sB[BUF] + c_ * 16);        \
    } } while (0)

    FSTAGE(0, 0);
    __syncthreads();
    int cur = 0;
    for (int k0 = 0; k0 < K; k0 += 32) {
        if (k0 + 32 < K) FSTAGE(cur ^ 1, k0 + 32);
        bf16x8 af[2], bfr[4];
        #pragma unroll
        for (int i = 0; i < 2; ++i)
            af[i] = *(const bf16x8*)&sA[cur][(wm + i * 16 + l15) * 32 + rq];
        #pragma unroll
        for (int i = 0; i < 4; ++i)
            bfr[i] = *(const bf16x8*)&sB[cur][(wn + i * 16 + l15) * 32 + rq];
        #pragma unroll
        for (int mi = 0; mi < 2; ++mi)
            #pragma unroll
            for (int ni = 0; ni < 4; ++ni)
                acc[mi][ni] = mfma16(af[mi], bfr[ni], acc[mi][ni]);
        __syncthreads();
        cur ^= 1;
    }
#undef FSTAGE

    #pragma unroll
    for (int ni = 0; ni < 4; ++ni) {
        const int n  = bn * 128 + wn + ni * 16 + l15;
        const float bv = bias[n];
        #pragma unroll
        for (int mi = 0; mi < 2; ++mi) {
            const int m0 = bm * 64 + wm + mi * 16 + quad * 4;
            #pragma unroll
            for (int r = 0; r < 4; ++r)
                C[(size_t)(m0 + r) * N + n] = acc[mi][ni][r] + bv;
        }
    }
}

// ---------------- Flash attention v11 (split-K, private partials) -----------
// unchanged from v11.
__global__ __launch_bounds__(256, 4) void attn_k(const bf16* __restrict__ Q,
                                                 const bf16* __restrict__ K,
                                                 const bf16* __restrict__ Vt,
                                                 const bf16* __restrict__ validB,
                                                 float* __restrict__ Opart,
                                                 float* __restrict__ Lpart,
                                                 bf16* __restrict__ Aout) {
    __shared__ bf16 sK_[2 * 128 * 32];   // 16K [kk][krow][32]
    __shared__ bf16 sV[4 * 64 * 32];     // 16K [kc][dv][32]   (V^T)
    const int tid  = threadIdx.x;
    const int l15  = tid & 15;
    const int quad = (tid & 63) >> 4;
    const int wid  = tid >> 6;           // 0..3 -> q quarter
    const int bh   = blockIdx.x & 31;
    const int b    = bh >> 4;
    const int h    = bh & 15;

    const uint32_t itm = g_items[blockIdx.x >> 5];
    const int qt  = itm & 255;
    const int kt0 = (itm >> 8) & 255;
    const int kte = (itm >> 16) & 255;
    const int nkt = (qt >> 1) + 1;       // full causal range (for diag test)
    const bool split = (qt >= 18);

    const bf16* Qg = Q  + (size_t)bh * S_ * HD;
    const bf16* Kg = K  + (size_t)bh * S_ * HD;
    const bf16* Vg = Vt + (size_t)bh * HD * S_;
    const bf16* vB = validB + b * S_;

    // Q B-frags: n=q=l15, k=kk*32+quad*8+jj
    bf16x8 qb[2];
    #pragma unroll
    for (int kk = 0; kk < 2; ++kk)
        qb[kk] = *(const bf16x8*)&Qg[(qt * 64 + wid * 16 + l15) * HD + kk * 32 + quad * 8];

    // permuted K row: lane l15 of frag f holds key (l15>>2)*8 + f*4 + (l15&3)
    const int krow0 = (l15 >> 2) * 8 + (l15 & 3);
    const int qg    = qt * 64 + wid * 16 + l15;   // this lane's global q (col)
    // conflict-free swizzled chunk offsets (elements)
    const int ckx = (quad ^ (((l15 >> 1) & 1) | (((l15 >> 2) & 1) << 1))) * 8;
    const int cvx = (quad ^ (((l15 >> 1) & 1) | (((l15 >> 3) & 1) << 1))) * 8;

    f32x4 o[4]  = {};                    // O^T: rows dv=dvf*16+quad*4+r, col q=l15
    f32x4 lacc  = {};                    // l[q], replicated

    for (int kt = kt0; kt < kte; ++kt) {
        __syncthreads();                 // prev compute done with sK_/sV
        #pragma unroll
        for (int it = 0; it < 4; ++it) {
            int c = it * 256 + tid;
            { int pl = c >> 9, row = (c >> 2) & 127, c8 = c & 3;
              int sw = c8 ^ (((row >> 1) & 1) | (((row >> 3) & 1) << 1));
              lds16(Kg + ((size_t)kt * 128 + row) * HD + pl * 32 + sw * 8,
                    (char*)sK_ + c * 16); }
            { int kc = c >> 8, dv = (c >> 2) & 63, c8 = c & 3;
              int sw = c8 ^ (((dv >> 1) & 1) | (((dv >> 3) & 1) << 1));
              lds16(Vg + (size_t)kt * 128 + (size_t)dv * S_ + kc * 32 + sw * 8,
                    (char*)sV + c * 16); }
        }
        // valid A-frags for the 4 key groups (tiny, L1-resident)
        bf16x8 vf[4];
        #pragma unroll
        for (int g = 0; g < 4; ++g)
            vf[g] = *(const bf16x8*)&vB[kt * 128 + g * 32 + quad * 8];
        __syncthreads();                 // staging drained & visible

        const bool lastt = (kt == nkt - 1);
        #pragma unroll
        for (int g = 0; g < 4; ++g) {
            // S^T for 32-key group g: C rows = keys (permuted back), cols = q
            f32x4 s[2] = {};
            #pragma unroll
            for (int f = 0; f < 2; ++f)
                #pragma unroll
                for (int kk = 0; kk < 2; ++kk) {
                    bf16x8 ka = *(const bf16x8*)
                        &sK_[(kk * 128 + g * 32 + krow0 + f * 4) * 32 + ckx];
                    s[f] = mfma16(ka, qb[kk], s[f]);
                }
            // exp2 -> P^T B-frag (lane-local pack); causal only on last tile
            bf16x8 pb;
            #pragma unroll
            for (int f = 0; f < 2; ++f)
                #pragma unroll
                for (int r = 0; r < 4; ++r) {
                    float v = s[f][r];
                    if (lastt && (kt * 128 + g * 32 + quad * 8 + f * 4 + r > qg))
                        v = NEG_BIG;
                    pb[f * 4 + r] = (bf16)exp2f(v);
                }
            lacc = mfma16(vf[g], pb, lacc);          // l += valid . P^T
            #pragma unroll
            for (int dvf = 0; dvf < 4; ++dvf) {
                bf16x8 va = *(const bf16x8*)
                    &sV[(g * 64 + dvf * 16 + l15) * 32 + cvx];
                o[dvf] = mfma16(va, pb, o[dvf]);     // O^T += V^T P^T
            }
        }
    }

    if (split) {
        // private partial slot: plain stores, no contention
        const int sidx = (qt - 18) * 2 + (kt0 ? 1 : 0);
        const int slot = bh * SLOTS_PER_BH + sidx;
        const int q    = wid * 16 + l15;
        float* Ob = Opart + ((size_t)slot << 12) + q * 64 + quad * 4;
        #pragma unroll
        for (int dvf = 0; dvf < 4; ++dvf)
            *(f32x4*)(Ob + dvf * 16) = o[dvf];
        if (quad == 0) Lpart[slot * 64 + q] = lacc[0];
    } else {
        // final: lane holds O[q][dv=dvf*16+quad*4+r], l[q]
        const float inv = 1.f / lacc[0];
        const size_t base = ((size_t)b * S_ + qg) * D_ + h * HD + quad * 4;
        #pragma unroll
        for (int dvf = 0; dvf < 4; ++dvf) {
            bf16x4 pk;
            #pragma unroll
            for (int r = 0; r < 4; ++r) pk[r] = (bf16)(o[dvf][r] * inv);
            *(bf16x4*)&Aout[base + dvf * 16] = pk;
        }
    }
}

// ---------------- combine split-K partials -> Aw (qt >= 18 only) ------------
// 229376 threads: (bh 32) x (qth 14) x (q 64) x (dv-chunk 8), 896 blocks.
__global__ __launch_bounds__(256) void combine_k(const float* __restrict__ Opart,
                                                 const float* __restrict__ Lpart,
                                                 bf16* __restrict__ Aw) {
    const int gid  = blockIdx.x * 256 + threadIdx.x;
    const int dc   = gid & 7;
    const int q    = (gid >> 3) & 63;
    const int rest = gid >> 9;           // 0..447
    const int qth  = rest % NSPLIT_QT;
    const int bh   = rest / NSPLIT_QT;
    const int slot0 = bh * SLOTS_PER_BH + qth * 2;
    const float l = Lpart[slot0 * 64 + q] + Lpart[(slot0 + 1) * 64 + q];
    const float inv = 1.f / l;
    const float* O0 = Opart + ((size_t)slot0 << 12) + q * 64 + dc * 8;
    const float* O1 = O0 + 4096;
    const float4 a0 = *(const float4*)O0;
    const float4 a1 = *(const float4*)(O0 + 4);
    const float4 b0 = *(const float4*)O1;
    const float4 b1 = *(const float4*)(O1 + 4);
    bf16x8 p;
    p[0] = (bf16)((a0.x + b0.x) * inv); p[1] = (bf16)((a0.y + b0.y) * inv);
    p[2] = (bf16)((a0.z + b0.z) * inv); p[3] = (bf16)((a0.w + b0.w) * inv);
    p[4] = (bf16)((a1.x + b1.x) * inv); p[5] = (bf16)((a1.y + b1.y) * inv);
    p[6] = (bf16)((a1.z + b1.z) * inv); p[7] = (bf16)((a1.w + b1.w) * inv);
    const int b = bh >> 4, h = bh & 15;
    const int s = (18 + qth) * 64 + q;
    *(bf16x8*)&Aw[((size_t)(b * S_ + s)) * D_ + h * HD + dc * 8] = p;
}

extern "C" void kernel_launch(void* const* d_in, const int* in_sizes, int n_in,
                              void* d_out, int out_size, void* d_ws, size_t ws_size,
                              hipStream_t stream) {
    const float* X   = (const float*)d_in[0];
    const float* pm  = (const float*)d_in[1];
    const float* wq  = (const float*)d_in[2];
    const float* bq  = (const float*)d_in[3];
    const float* wk  = (const float*)d_in[4];
    const float* bk  = (const float*)d_in[5];
    const float* wv  = (const float*)d_in[6];
    const float* bvb = (const float*)d_in[7];
    const float* wo  = (const float*)d_in[8];
    const float* bo  = (const float*)d_in[9];
    float* out = (float*)d_out;

    char* ws = (char*)d_ws;
    bf16* Xb  = (bf16*)(ws);                  // 4M elems  8 MiB (dead after qkv)
    bf16* Wqb = (bf16*)(ws + (8u  << 20));    // 2 MiB each (dead after qkv)
    bf16* Wkb = (bf16*)(ws + (10u << 20));
    bf16* Wvb = (bf16*)(ws + (12u << 20));
    bf16* Wob = (bf16*)(ws + (14u << 20));    // live until gemm_fin
    bf16* Qw  = (bf16*)(ws + (16u << 20));    // [B,H,S,64]  8 MiB
    bf16* Kw  = (bf16*)(ws + (24u << 20));    // [B,H,S,64]  8 MiB
    bf16* Vw  = (bf16*)(ws + (32u << 20));    // [B,H,64,S]  8 MiB
    bf16* Aw  = (bf16*)(ws + (40u << 20));    // [B*S, 1024] 8 MiB
    // split-K partials overlay the dead Xb..Wvb region (14 MiB exactly):
    float* Opart = (float*)(ws);
    bf16*  validB = (bf16*)(ws + (48u << 20));          // 8 KiB
    float* Lpart  = (float*)(ws + (48u << 20) + 65536); // 224 KiB

    convert_k<<<dim3(8192), dim3(256), 0, stream>>>(X, wq, wk, wv, wo, pm,
                                                    Xb, validB);
    gemm_qkv<<<dim3(24, 32), dim3(256), 0, stream>>>(Xb, Wqb, Wkb, Wvb,
                                                     bq, bk, bvb, pm,
                                                     Qw, Kw, Vw);
    attn_k<<<dim3(1472), dim3(256), 0, stream>>>(Qw, Kw, Vw, validB,
                                                 Opart, Lpart, Aw);
    combine_k<<<dim3(896), dim3(256), 0, stream>>>(Opart, Lpart, Aw);
    gemm_fin<<<dim3(512), dim3(256), 0, stream>>>(Aw, Wob, bo, out);
}